// Round 1
// baseline (19482.204 us; speedup 1.0000x reference)
//
#include <hip/hip_runtime.h>
#include <math.h>

// Problem constants
#define CB 16
#define CS 400
#define CT 51
#define CTM1 50
#define CV 50000
#define CE 128
#define CH 256
#define CMAXOOV 50
#define CEXT (CV + CMAXOOV)

__device__ __forceinline__ float wave_sum(float x) {
#pragma unroll
  for (int o = 32; o > 0; o >>= 1) x += __shfl_xor(x, o);
  return x;
}
__device__ __forceinline__ float wave_max(float x) {
#pragma unroll
  for (int o = 32; o > 0; o >>= 1) x = fmaxf(x, __shfl_xor(x, o));
  return x;
}
__device__ __forceinline__ float sigm(float x) { return 1.f / (1.f + expf(-x)); }

// ---------------------------------------------------------------------------
// P0: Wh_h[b,s,k] = sum_h enc[b,s,h] * W_h[k,h]; copy_idx; init h,c,cov
// grid = B*S blocks, 256 threads
// ---------------------------------------------------------------------------
__global__ __launch_bounds__(256) void p0_precompute(
    const float* __restrict__ enc, const float* __restrict__ W_h,
    const float* __restrict__ hidden, const float* __restrict__ cell,
    const int* __restrict__ src_ids, const int* __restrict__ src_oov,
    float* __restrict__ Wh_h, float* __restrict__ h, float* __restrict__ c,
    float* __restrict__ cov, int* __restrict__ copy_idx) {
  int row = blockIdx.x;  // b*S + s
  int tid = threadIdx.x;
  __shared__ float er[CH];
  er[tid] = enc[(size_t)row * CH + tid];
  __syncthreads();
  const float* wr = W_h + (size_t)tid * CH;
  float a0 = 0.f, a1 = 0.f, a2 = 0.f, a3 = 0.f;
  for (int k = 0; k < CH; k += 4) {
    float4 w = *(const float4*)(wr + k);
    a0 += er[k] * w.x;
    a1 += er[k + 1] * w.y;
    a2 += er[k + 2] * w.z;
    a3 += er[k + 3] * w.w;
  }
  Wh_h[(size_t)row * CH + tid] = a0 + a1 + a2 + a3;
  if (tid == 0) {
    int ov = src_oov[row];
    copy_idx[row] = (ov >= 0) ? (CV + ov) : src_ids[row];
    cov[row] = 0.f;
  }
  int b = row / CS, s = row % CS;
  if (s == 0) {
    h[b * CH + tid] = hidden[b * CH + tid];
    c[b * CH + tid] = cell[b * CH + tid];
  }
}

// ---------------------------------------------------------------------------
// K1: (scatter prev copy-dist) + attention + softmax + coverage + context +
//     LSTM cell + p_gen.  grid = B blocks, 1024 threads
// ---------------------------------------------------------------------------
__global__ __launch_bounds__(1024) void k1_attn_lstm(
    int t, const int* __restrict__ tgt, const float* __restrict__ enc,
    const int* __restrict__ src_lens, const float* __restrict__ embedding,
    const float* __restrict__ W_s, const float* __restrict__ w_c,
    const float* __restrict__ v_vec, const float* __restrict__ b_attn,
    const float* __restrict__ W_ih, const float* __restrict__ W_hh,
    const float* __restrict__ b_ih, const float* __restrict__ b_hh,
    const float* __restrict__ W_pg, const float* __restrict__ b_pg,
    const float* __restrict__ Wh_h, const int* __restrict__ copy_idx,
    float* __restrict__ h, float* __restrict__ c, float* __restrict__ cov,
    float* __restrict__ attn_ws, float* __restrict__ ctx_ws,
    float* __restrict__ p_gen_ws, float* __restrict__ rowsum_ws,
    float* __restrict__ covloss_ws, float* __restrict__ dout) {
  const int b = blockIdx.x;
  const int tid = threadIdx.x;
  const int lane = tid & 63, wid = tid >> 6;

  __shared__ float sh_h[CH];
  __shared__ float sh_x[CE + CH];  // [emb | context]
  __shared__ float sh_hWs[CH];
  __shared__ float sh_attn[CS];
  __shared__ float sh_gates[4 * CH];
  __shared__ float sh_hnew[CH];
  __shared__ float red[16];
  __shared__ float sh_stat[2];

  // 0: scatter previous step's copy distribution into its (finished) dist slab
  if (t > 0) {
    float pg1 = 1.f - p_gen_ws[b];
    for (int s = tid; s < CS; s += 1024) {
      int idx = copy_idx[b * CS + s];
      atomicAdd(dout + ((size_t)(b * CTM1 + (t - 1))) * CEXT + idx,
                pg1 * attn_ws[b * CS + s]);
    }
  }
  // load h_old, embedding row
  if (tid < CH) sh_h[tid] = h[b * CH + tid];
  if (tid < CE) {
    int y = tgt[b * CT + t];
    sh_x[tid] = embedding[(size_t)y * CE + tid];
  }
  if (tid == 0) rowsum_ws[b] = 0.f;
  __syncthreads();

  // hWs[k] = sum_h h_old[h] * W_s[k,h]
  if (tid < CH) {
    const float* wr = W_s + (size_t)tid * CH;
    float a0 = 0.f, a1 = 0.f, a2 = 0.f, a3 = 0.f;
    for (int k = 0; k < CH; k += 4) {
      float4 w = *(const float4*)(wr + k);
      a0 += sh_h[k] * w.x;
      a1 += sh_h[k + 1] * w.y;
      a2 += sh_h[k + 2] * w.z;
      a3 += sh_h[k + 3] * w.w;
    }
    sh_hWs[tid] = a0 + a1 + a2 + a3;
  }
  __syncthreads();

  // scores[s] = v . tanh(Wh_h[b,s,:] + hWs + cov*w_c + b_attn)  (wave per s)
  {
    const float ba = b_attn[0];
    const int len = src_lens[b];
    for (int s = wid; s < CS; s += 16) {
      float cv = cov[b * CS + s];
      const float* whr = Wh_h + ((size_t)(b * CS + s)) * CH;
      float p = 0.f;
      for (int k = lane; k < CH; k += 64) {
        float a = whr[k] + sh_hWs[k] + cv * w_c[k] + ba;
        p += tanhf(a) * v_vec[k];
      }
      p = wave_sum(p);
      if (lane == 0) sh_attn[s] = (s >= len) ? -1e9f : p;
    }
  }
  __syncthreads();

  // masked softmax over S
  float sc = (tid < CS) ? sh_attn[tid] : -1e30f;
  float m = wave_max(sc);
  if (lane == 0) red[wid] = m;
  __syncthreads();
  if (tid == 0) {
    float mm = red[0];
    for (int i = 1; i < 16; ++i) mm = fmaxf(mm, red[i]);
    sh_stat[0] = mm;
  }
  __syncthreads();
  m = sh_stat[0];
  float e = (tid < CS) ? expf(sc - m) : 0.f;
  float ssum = wave_sum(e);
  if (lane == 0) red[wid] = ssum;
  __syncthreads();
  if (tid == 0) {
    float s2 = 0.f;
    for (int i = 0; i < 16; ++i) s2 += red[i];
    sh_stat[1] = s2;
  }
  __syncthreads();
  float covloss_p = 0.f;
  if (tid < CS) {
    float av = e / sh_stat[1];
    sh_attn[tid] = av;
    attn_ws[b * CS + tid] = av;
    float cvold = cov[b * CS + tid];
    covloss_p = fminf(av, cvold);
    cov[b * CS + tid] = cvold + av;  // coverage update (uses old cov above)
  }
  float cl = wave_sum(covloss_p);
  if (lane == 0) red[wid] = cl;
  __syncthreads();
  if (tid == 0) {
    float s2 = 0.f;
    for (int i = 0; i < 16; ++i) s2 += red[i];
    covloss_ws[t * CB + b] = s2;
  }
  // context[k] = sum_s attn[s] * enc[b,s,k]
  if (tid < CH) {
    const float* er = enc + ((size_t)b * CS) * CH + tid;
    float a0 = 0.f, a1 = 0.f, a2 = 0.f, a3 = 0.f;
    for (int s = 0; s < CS; s += 4) {
      a0 += sh_attn[s] * er[(size_t)s * CH];
      a1 += sh_attn[s + 1] * er[(size_t)(s + 1) * CH];
      a2 += sh_attn[s + 2] * er[(size_t)(s + 2) * CH];
      a3 += sh_attn[s + 3] * er[(size_t)(s + 3) * CH];
    }
    float ctxv = a0 + a1 + a2 + a3;
    sh_x[CE + tid] = ctxv;
    ctx_ws[b * CH + tid] = ctxv;
  }
  __syncthreads();

  // LSTM gates: gates[j] = x.W_ih[j,:] + h.W_hh[j,:] + b_ih[j] + b_hh[j]
  {
    int j = tid;
    const float* wi = W_ih + (size_t)j * (CE + CH);
    float a0 = 0.f, a1 = 0.f, a2 = 0.f, a3 = 0.f;
    for (int k = 0; k < CE + CH; k += 4) {
      float4 w = *(const float4*)(wi + k);
      a0 += sh_x[k] * w.x;
      a1 += sh_x[k + 1] * w.y;
      a2 += sh_x[k + 2] * w.z;
      a3 += sh_x[k + 3] * w.w;
    }
    const float* wh = W_hh + (size_t)j * CH;
    for (int k = 0; k < CH; k += 4) {
      float4 w = *(const float4*)(wh + k);
      a0 += sh_h[k] * w.x;
      a1 += sh_h[k + 1] * w.y;
      a2 += sh_h[k + 2] * w.z;
      a3 += sh_h[k + 3] * w.w;
    }
    sh_gates[j] = a0 + a1 + a2 + a3 + b_ih[j] + b_hh[j];
  }
  __syncthreads();
  // cell update (torch gate order i,f,g,o)
  if (tid < CH) {
    float gi = sh_gates[tid], gf = sh_gates[CH + tid];
    float gg = sh_gates[2 * CH + tid], go = sh_gates[3 * CH + tid];
    float co = c[b * CH + tid];
    float cn = sigm(gf) * co + sigm(gi) * tanhf(gg);
    float hn = sigm(go) * tanhf(cn);
    c[b * CH + tid] = cn;
    h[b * CH + tid] = hn;
    sh_hnew[tid] = hn;
  }
  __syncthreads();
  // p_gen = sigmoid([h_new, context, emb] . W_pg + b_pg)
  float zp = 0.f;
  if (tid < 2 * CH + CE) {
    float z = (tid < CH) ? sh_hnew[tid]
              : (tid < 2 * CH) ? sh_x[CE + (tid - CH)]
                               : sh_x[tid - 2 * CH];
    zp = z * W_pg[tid];
  }
  float zs = wave_sum(zp);
  if (lane == 0) red[wid] = zs;
  __syncthreads();
  if (tid == 0) {
    float s2 = 0.f;
    for (int i = 0; i < 16; ++i) s2 += red[i];
    p_gen_ws[b] = sigm(s2 + b_pg[0]);
  }
}

// ---------------------------------------------------------------------------
// K2: logits[b,v] = [h_new|ctx] . W_out[v,:] + b_out[v]; explog = exp(logit);
//     rowsum[b] += partial sums.  grid = ceil(V/256) blocks, 256 threads.
//     (no max-subtraction: |logit| <~ 5 with these weight scales)
// ---------------------------------------------------------------------------
__global__ __launch_bounds__(256) void k2_logits(
    const float* __restrict__ W_out, const float* __restrict__ b_out,
    const float* __restrict__ h, const float* __restrict__ ctx,
    float* __restrict__ explog, float* __restrict__ rowsum) {
  __shared__ float hc[CB][2 * CH];  // 32 KiB
  int tid = threadIdx.x;
  for (int i = tid; i < CB * 2 * CH; i += 256) {
    int bb = i >> 9, k = i & 511;
    hc[bb][k] = (k < CH) ? h[bb * CH + k] : ctx[bb * CH + (k - CH)];
  }
  __syncthreads();
  int v = blockIdx.x * 256 + tid;
  float partial[CB];
#pragma unroll
  for (int bb = 0; bb < CB; ++bb) partial[bb] = 0.f;
  if (v < CV) {
    const float* wr = W_out + (size_t)v * (2 * CH);
    float acc[CB];
#pragma unroll
    for (int bb = 0; bb < CB; ++bb) acc[bb] = 0.f;
    for (int k = 0; k < 2 * CH; k += 4) {
      float4 w = *(const float4*)(wr + k);
#pragma unroll
      for (int bb = 0; bb < CB; ++bb) {
        float4 x = *(const float4*)(&hc[bb][k]);
        acc[bb] += x.x * w.x + x.y * w.y + x.z * w.z + x.w * w.w;
      }
    }
    float bo = b_out[v];
#pragma unroll
    for (int bb = 0; bb < CB; ++bb) {
      float ev = expf(acc[bb] + bo);
      explog[(size_t)bb * CV + v] = ev;
      partial[bb] = ev;
    }
  }
  int lane = tid & 63;
#pragma unroll
  for (int bb = 0; bb < CB; ++bb) {
    float s = wave_sum(partial[bb]);
    if (lane == 0) atomicAdd(&rowsum[bb], s);
  }
}

// ---------------------------------------------------------------------------
// K3: final[b,v] = p_gen * vocab_dist (v<V), 0 for pad slots.
//     grid = (ceil(EXT/256), B)
// ---------------------------------------------------------------------------
__global__ __launch_bounds__(256) void k3_final(
    int t, const float* __restrict__ explog, const float* __restrict__ rowsum,
    const float* __restrict__ p_gen, float* __restrict__ dout) {
  int vv = blockIdx.x * 256 + threadIdx.x;
  int b = blockIdx.y;
  if (vv >= CEXT) return;
  float val = 0.f;
  if (vv < CV) val = p_gen[b] * explog[(size_t)b * CV + vv] / rowsum[b];
  dout[((size_t)(b * CTM1 + t)) * CEXT + vv] = val;
}

// ---------------------------------------------------------------------------
// K4 epilogue: last step's scatter, hT/cT, coverage_loss. grid = 1 block.
// ---------------------------------------------------------------------------
__global__ __launch_bounds__(1024) void k4_epilogue(
    const float* __restrict__ h, const float* __restrict__ c,
    const float* __restrict__ attn_ws, const float* __restrict__ p_gen_ws,
    const int* __restrict__ copy_idx, const float* __restrict__ covloss_ws,
    float* __restrict__ dout) {
  int tid = threadIdx.x;
  for (int i = tid; i < CB * CS; i += 1024) {
    int b = i / CS;
    float val = (1.f - p_gen_ws[b]) * attn_ws[i];
    atomicAdd(dout + ((size_t)(b * CTM1 + (CTM1 - 1))) * CEXT + copy_idx[i],
              val);
  }
  const size_t D0 = (size_t)CB * CTM1 * CEXT;
  for (int i = tid; i < CB * CH; i += 1024) {
    dout[D0 + i] = h[i];
    dout[D0 + CB * CH + i] = c[i];
  }
  float p = 0.f;
  for (int i = tid; i < CTM1 * CB; i += 1024) p += covloss_ws[i];
  __shared__ float red[16];
  float s = wave_sum(p);
  int lane = tid & 63, wid = tid >> 6;
  if (lane == 0) red[wid] = s;
  __syncthreads();
  if (tid == 0) {
    float t2 = 0.f;
    for (int i = 0; i < 16; ++i) t2 += red[i];
    dout[D0 + 2 * CB * CH] = t2 / (float)(CTM1 * CB);
  }
}

// ---------------------------------------------------------------------------
extern "C" void kernel_launch(void* const* d_in, const int* in_sizes, int n_in,
                              void* d_out, int out_size, void* d_ws,
                              size_t ws_size, hipStream_t stream) {
  const int* tgt = (const int*)d_in[0];
  const float* hidden = (const float*)d_in[1];
  const float* cell = (const float*)d_in[2];
  const float* enc = (const float*)d_in[3];
  const int* src_lens = (const int*)d_in[4];
  const int* src_ids = (const int*)d_in[5];
  const int* src_oov = (const int*)d_in[6];
  const float* embedding = (const float*)d_in[7];
  const float* W_h = (const float*)d_in[8];
  const float* W_s = (const float*)d_in[9];
  const float* w_c = (const float*)d_in[10];
  const float* v_vec = (const float*)d_in[11];
  const float* b_attn = (const float*)d_in[12];
  const float* W_ih = (const float*)d_in[13];
  const float* W_hh = (const float*)d_in[14];
  const float* b_ih = (const float*)d_in[15];
  const float* b_hh = (const float*)d_in[16];
  const float* W_pg = (const float*)d_in[17];
  const float* b_pg = (const float*)d_in[18];
  const float* W_out = (const float*)d_in[19];
  const float* b_out = (const float*)d_in[20];
  float* dout = (float*)d_out;

  // workspace layout (floats)
  float* ws = (float*)d_ws;
  float* Wh_h = ws;                        // B*S*H
  float* h = Wh_h + (size_t)CB * CS * CH;  // B*H
  float* c = h + CB * CH;                  // B*H
  float* cov = c + CB * CH;                // B*S
  float* attn = cov + CB * CS;             // B*S
  float* ctx = attn + CB * CS;             // B*H
  float* p_gen = ctx + CB * CH;            // B
  float* rowsum = p_gen + CB;              // B
  float* covloss = rowsum + CB;            // TM1*B
  float* explog = covloss + CTM1 * CB;     // B*V
  int* copy_idx = (int*)(explog + (size_t)CB * CV);  // B*S ints

  p0_precompute<<<CB * CS, 256, 0, stream>>>(enc, W_h, hidden, cell, src_ids,
                                             src_oov, Wh_h, h, c, cov,
                                             copy_idx);
  for (int t = 0; t < CTM1; ++t) {
    k1_attn_lstm<<<CB, 1024, 0, stream>>>(
        t, tgt, enc, src_lens, embedding, W_s, w_c, v_vec, b_attn, W_ih, W_hh,
        b_ih, b_hh, W_pg, b_pg, Wh_h, copy_idx, h, c, cov, attn, ctx, p_gen,
        rowsum, covloss, dout);
    k2_logits<<<(CV + 255) / 256, 256, 0, stream>>>(W_out, b_out, h, ctx,
                                                    explog, rowsum);
    k3_final<<<dim3((CEXT + 255) / 256, CB), 256, 0, stream>>>(t, explog,
                                                               rowsum, p_gen,
                                                               dout);
  }
  k4_epilogue<<<1, 1024, 0, stream>>>(h, c, attn, p_gen, copy_idx, covloss,
                                      dout);
}

// Round 2
// 10400.845 us; speedup vs baseline: 1.8731x; 1.8731x over previous
//
#include <hip/hip_runtime.h>
#include <math.h>

// Problem constants
#define CB 16
#define CS 400
#define CT 51
#define CTM1 50
#define CV 50000
#define CE 128
#define CH 256
#define CMAXOOV 50
#define CEXT (CV + CMAXOOV)

typedef __attribute__((ext_vector_type(4))) float f32x4;
typedef __attribute__((ext_vector_type(8))) short short8;

__device__ __forceinline__ float wave_sum(float x) {
#pragma unroll
  for (int o = 32; o > 0; o >>= 1) x += __shfl_xor(x, o);
  return x;
}
__device__ __forceinline__ float wave_max(float x) {
#pragma unroll
  for (int o = 32; o > 0; o >>= 1) x = fmaxf(x, __shfl_xor(x, o));
  return x;
}
__device__ __forceinline__ float sigm(float x) { return 1.f / (1.f + expf(-x)); }
__device__ __forceinline__ unsigned short f2bf(float f) {
  union { float f; unsigned u; } x;
  x.f = f;
  unsigned r = x.u + 0x7FFFu + ((x.u >> 16) & 1u);  // RNE
  return (unsigned short)(r >> 16);
}

// ---------------------------------------------------------------------------
// PW: convert W_out (fp32, V x 2H) to bf16, once. grid = V*2H/(256*8) blocks.
// ---------------------------------------------------------------------------
__global__ __launch_bounds__(256) void pw_convert(
    const float* __restrict__ W, unsigned short* __restrict__ Wb) {
  size_t i = ((size_t)blockIdx.x * 256 + threadIdx.x) * 8;
  float4 a = *(const float4*)(W + i);
  float4 b = *(const float4*)(W + i + 4);
  short8 o;
  o[0] = (short)f2bf(a.x); o[1] = (short)f2bf(a.y);
  o[2] = (short)f2bf(a.z); o[3] = (short)f2bf(a.w);
  o[4] = (short)f2bf(b.x); o[5] = (short)f2bf(b.y);
  o[6] = (short)f2bf(b.z); o[7] = (short)f2bf(b.w);
  *(short8*)(Wb + i) = o;
}

// ---------------------------------------------------------------------------
// P0: Wh_h[b,s,k] = sum_j enc[b,s,j] * W_h[k,j]; copy_idx; init h,c,cov
// grid = B*S/8 blocks (8 rows per block), 256 threads
// ---------------------------------------------------------------------------
__global__ __launch_bounds__(256) void p0_precompute(
    const float* __restrict__ enc, const float* __restrict__ W_h,
    const float* __restrict__ hidden, const float* __restrict__ cell,
    const int* __restrict__ src_ids, const int* __restrict__ src_oov,
    float* __restrict__ Wh_h, float* __restrict__ h, float* __restrict__ c,
    float* __restrict__ cov, int* __restrict__ copy_idx) {
  int row0 = blockIdx.x * 8;
  int tid = threadIdx.x;
  __shared__ float er[8][CH];
  for (int i = tid; i < 8 * CH; i += 256)
    er[i >> 8][i & 255] = enc[(size_t)row0 * CH + i];
  if (tid < 8) {
    int row = row0 + tid;
    int ov = src_oov[row];
    copy_idx[row] = (ov >= 0) ? (CV + ov) : src_ids[row];
    cov[row] = 0.f;
  }
  if ((row0 % CS) == 0) {
    int b = row0 / CS;
    h[b * CH + tid] = hidden[b * CH + tid];
    c[b * CH + tid] = cell[b * CH + tid];
  }
  __syncthreads();
  const float* wr = W_h + (size_t)tid * CH;
  float acc[8];
#pragma unroll
  for (int r = 0; r < 8; ++r) acc[r] = 0.f;
  for (int j = 0; j < CH; j += 4) {
    float4 w = *(const float4*)(wr + j);
#pragma unroll
    for (int r = 0; r < 8; ++r) {
      float4 e = *(const float4*)(&er[r][j]);
      acc[r] += e.x * w.x + e.y * w.y + e.z * w.z + e.w * w.w;
    }
  }
#pragma unroll
  for (int r = 0; r < 8; ++r) Wh_h[(size_t)(row0 + r) * CH + tid] = acc[r];
}

// ---------------------------------------------------------------------------
// K1: (scatter prev copy-dist) + attention + softmax + coverage + context +
//     LSTM cell + p_gen + write A_bf16 = [h_new|ctx].  grid = B, 1024 thr.
// ---------------------------------------------------------------------------
__global__ __launch_bounds__(1024) void k1_attn_lstm(
    int t, const int* __restrict__ tgt, const float* __restrict__ enc,
    const int* __restrict__ src_lens, const float* __restrict__ embedding,
    const float* __restrict__ W_s, const float* __restrict__ w_c,
    const float* __restrict__ v_vec, const float* __restrict__ b_attn,
    const float* __restrict__ W_ih, const float* __restrict__ W_hh,
    const float* __restrict__ b_ih, const float* __restrict__ b_hh,
    const float* __restrict__ W_pg, const float* __restrict__ b_pg,
    const float* __restrict__ Wh_h, const int* __restrict__ copy_idx,
    float* __restrict__ h, float* __restrict__ c, float* __restrict__ cov,
    float* __restrict__ attn_ws, float* __restrict__ ctx_ws,
    float* __restrict__ p_gen_ws, float* __restrict__ rowsum_ws,
    float* __restrict__ covloss_ws, unsigned short* __restrict__ A_bf16,
    float* __restrict__ dout) {
  const int b = blockIdx.x;
  const int tid = threadIdx.x;
  const int lane = tid & 63, wid = tid >> 6;

  __shared__ float sh_h[CH];
  __shared__ float sh_x[CE + CH];  // [emb | context]
  __shared__ float sh_hWs[CH];
  __shared__ float sh_attn[CS];
  __shared__ float sh_gates[4 * CH];
  __shared__ float sh_hnew[CH];
  __shared__ float sh_pctx[16][CH];  // per-wave partial context
  __shared__ float red[16];
  __shared__ float sh_stat[2];

  // 0: scatter previous step's copy distribution into its (finished) slab
  if (t > 0) {
    float pg1 = 1.f - p_gen_ws[b];
    for (int s = tid; s < CS; s += 1024) {
      int idx = copy_idx[b * CS + s];
      atomicAdd(dout + ((size_t)(b * CTM1 + (t - 1))) * CEXT + idx,
                pg1 * attn_ws[b * CS + s]);
    }
  }
  // load h_old, embedding row
  if (tid < CH) sh_h[tid] = h[b * CH + tid];
  if (tid < CE) {
    int y = tgt[b * CT + t];
    sh_x[tid] = embedding[(size_t)y * CE + tid];
  }
  if (tid == 0) rowsum_ws[b] = 0.f;
  __syncthreads();

  // hWs[k] = sum_j h_old[j] * W_s[k,j]
  if (tid < CH) {
    const float* wr = W_s + (size_t)tid * CH;
    float a0 = 0.f, a1 = 0.f, a2 = 0.f, a3 = 0.f;
    for (int k = 0; k < CH; k += 4) {
      float4 w = *(const float4*)(wr + k);
      a0 += sh_h[k] * w.x;
      a1 += sh_h[k + 1] * w.y;
      a2 += sh_h[k + 2] * w.z;
      a3 += sh_h[k + 3] * w.w;
    }
    sh_hWs[tid] = a0 + a1 + a2 + a3;
  }
  __syncthreads();

  // scores[s] = v . tanh(Wh_h[b,s,:] + hWs + cov*w_c + b_attn)  (wave per s)
  {
    const float ba = b_attn[0];
    const int len = src_lens[b];
    for (int s = wid; s < CS; s += 16) {
      float cv = cov[b * CS + s];
      const float* whr = Wh_h + ((size_t)(b * CS + s)) * CH;
      float p = 0.f;
      for (int k = lane; k < CH; k += 64) {
        float a = whr[k] + sh_hWs[k] + cv * w_c[k] + ba;
        p += tanhf(a) * v_vec[k];
      }
      p = wave_sum(p);
      if (lane == 0) sh_attn[s] = (s >= len) ? -1e9f : p;
    }
  }
  __syncthreads();

  // masked softmax over S
  float sc = (tid < CS) ? sh_attn[tid] : -1e30f;
  float m = wave_max(sc);
  if (lane == 0) red[wid] = m;
  __syncthreads();
  if (tid == 0) {
    float mm = red[0];
    for (int i = 1; i < 16; ++i) mm = fmaxf(mm, red[i]);
    sh_stat[0] = mm;
  }
  __syncthreads();
  m = sh_stat[0];
  float e = (tid < CS) ? expf(sc - m) : 0.f;
  float ssum = wave_sum(e);
  if (lane == 0) red[wid] = ssum;
  __syncthreads();
  if (tid == 0) {
    float s2 = 0.f;
    for (int i = 0; i < 16; ++i) s2 += red[i];
    sh_stat[1] = s2;
  }
  __syncthreads();
  float covloss_p = 0.f;
  if (tid < CS) {
    float av = e / sh_stat[1];
    sh_attn[tid] = av;
    attn_ws[b * CS + tid] = av;
    float cvold = cov[b * CS + tid];
    covloss_p = fminf(av, cvold);
    cov[b * CS + tid] = cvold + av;
  }
  float cl = wave_sum(covloss_p);
  if (lane == 0) red[wid] = cl;
  __syncthreads();
  if (tid == 0) {
    float s2 = 0.f;
    for (int i = 0; i < 16; ++i) s2 += red[i];
    covloss_ws[t * CB + b] = s2;
  }
  __syncthreads();

  // context[k] = sum_s attn[s]*enc[b,s,k] — wave-parallel over s, coalesced k
  {
    float pc0 = 0.f, pc1 = 0.f, pc2 = 0.f, pc3 = 0.f;
    for (int s = wid; s < CS; s += 16) {
      float a = sh_attn[s];
      const float* er = enc + ((size_t)(b * CS + s)) * CH;
      pc0 += a * er[lane];
      pc1 += a * er[lane + 64];
      pc2 += a * er[lane + 128];
      pc3 += a * er[lane + 192];
    }
    sh_pctx[wid][lane] = pc0;
    sh_pctx[wid][lane + 64] = pc1;
    sh_pctx[wid][lane + 128] = pc2;
    sh_pctx[wid][lane + 192] = pc3;
  }
  __syncthreads();
  if (tid < CH) {
    float s = 0.f;
#pragma unroll
    for (int w = 0; w < 16; ++w) s += sh_pctx[w][tid];
    sh_x[CE + tid] = s;
    ctx_ws[b * CH + tid] = s;
  }
  __syncthreads();

  // LSTM gates
  {
    int j = tid;
    const float* wi = W_ih + (size_t)j * (CE + CH);
    float a0 = 0.f, a1 = 0.f, a2 = 0.f, a3 = 0.f;
    for (int k = 0; k < CE + CH; k += 4) {
      float4 w = *(const float4*)(wi + k);
      a0 += sh_x[k] * w.x;
      a1 += sh_x[k + 1] * w.y;
      a2 += sh_x[k + 2] * w.z;
      a3 += sh_x[k + 3] * w.w;
    }
    const float* wh = W_hh + (size_t)j * CH;
    for (int k = 0; k < CH; k += 4) {
      float4 w = *(const float4*)(wh + k);
      a0 += sh_h[k] * w.x;
      a1 += sh_h[k + 1] * w.y;
      a2 += sh_h[k + 2] * w.z;
      a3 += sh_h[k + 3] * w.w;
    }
    sh_gates[j] = a0 + a1 + a2 + a3 + b_ih[j] + b_hh[j];
  }
  __syncthreads();
  if (tid < CH) {
    float gi = sh_gates[tid], gf = sh_gates[CH + tid];
    float gg = sh_gates[2 * CH + tid], go = sh_gates[3 * CH + tid];
    float co = c[b * CH + tid];
    float cn = sigm(gf) * co + sigm(gi) * tanhf(gg);
    float hn = sigm(go) * tanhf(cn);
    c[b * CH + tid] = cn;
    h[b * CH + tid] = hn;
    sh_hnew[tid] = hn;
  }
  __syncthreads();
  // A_bf16[b][k] = bf16([h_new | ctx])  (for MFMA k2)
  if (A_bf16 && tid < 2 * CH) {
    float val = (tid < CH) ? sh_hnew[tid] : sh_x[CE + (tid - CH)];
    A_bf16[b * (2 * CH) + tid] = f2bf(val);
  }
  // p_gen
  float zp = 0.f;
  if (tid < 2 * CH + CE) {
    float z = (tid < CH) ? sh_hnew[tid]
              : (tid < 2 * CH) ? sh_x[CE + (tid - CH)]
                               : sh_x[tid - 2 * CH];
    zp = z * W_pg[tid];
  }
  float zs = wave_sum(zp);
  if (lane == 0) red[wid] = zs;
  __syncthreads();
  if (tid == 0) {
    float s2 = 0.f;
    for (int i = 0; i < 16; ++i) s2 += red[i];
    p_gen_ws[b] = sigm(s2 + b_pg[0]);
  }
}

// ---------------------------------------------------------------------------
// K2 (MFMA): explog[b,v] = exp([h|ctx].W_out[v,:] + b_out[v]); rowsum atomics.
// grid = ceil(V/64), 256 threads (4 waves, one 16-v tile per wave).
// A layout [16][512] bf16; W_out_bf16 [V][512].
// mfma_f32_16x16x32_bf16: lane l holds A[m=l&15][k=(l>>4)*8+j], j=0..7;
//                          B[k=(l>>4)*8+j][n=l&15]; D: n=l&15, m=(l>>4)*4+r.
// ---------------------------------------------------------------------------
__global__ __launch_bounds__(256) void k2_logits_mfma(
    const unsigned short* __restrict__ Wb, const float* __restrict__ b_out,
    const unsigned short* __restrict__ A, float* __restrict__ explog,
    float* __restrict__ rowsum) {
  const int tid = threadIdx.x;
  const int lane = tid & 63, wid = tid >> 6;
  const int n = lane & 15, g = lane >> 4;
  const int vbase = blockIdx.x * 64 + wid * 16;
  const int v = vbase + n;
  const bool ok = v < CV;
  const int vc = ok ? v : CV - 1;

  const short8* ap = (const short8*)A;
  const short8* bp = (const short8*)Wb;
  short8 af[16], bf[16];
#pragma unroll
  for (int kt = 0; kt < 16; ++kt) af[kt] = ap[n * 64 + kt * 4 + g];
#pragma unroll
  for (int kt = 0; kt < 16; ++kt) bf[kt] = bp[(size_t)vc * 64 + kt * 4 + g];

  f32x4 acc = {0.f, 0.f, 0.f, 0.f};
#pragma unroll
  for (int kt = 0; kt < 16; ++kt)
    acc = __builtin_amdgcn_mfma_f32_16x16x32_bf16(af[kt], bf[kt], acc, 0, 0, 0);

  float bo = ok ? b_out[v] : 0.f;
  float ev[4];
#pragma unroll
  for (int r = 0; r < 4; ++r) {
    float e = ok ? expf(acc[r] + bo) : 0.f;
    ev[r] = e;
    if (ok) explog[(size_t)(g * 4 + r) * CV + v] = e;
  }
  // reduce across the 16 lanes of each quarter-group
#pragma unroll
  for (int r = 0; r < 4; ++r) {
#pragma unroll
    for (int o = 1; o < 16; o <<= 1) ev[r] += __shfl_xor(ev[r], o);
  }
  __shared__ float prs[4][16];
  if ((lane & 15) == 0) {
#pragma unroll
    for (int r = 0; r < 4; ++r) prs[wid][g * 4 + r] = ev[r];
  }
  __syncthreads();
  if (tid < 16) {
    float s = prs[0][tid] + prs[1][tid] + prs[2][tid] + prs[3][tid];
    atomicAdd(&rowsum[tid], s);
  }
}

// ---------------------------------------------------------------------------
// K2 (fp32 fallback — round-1 version)
// ---------------------------------------------------------------------------
__global__ __launch_bounds__(256) void k2_logits_fp32(
    const float* __restrict__ W_out, const float* __restrict__ b_out,
    const float* __restrict__ h, const float* __restrict__ ctx,
    float* __restrict__ explog, float* __restrict__ rowsum) {
  __shared__ float hc[CB][2 * CH];
  int tid = threadIdx.x;
  for (int i = tid; i < CB * 2 * CH; i += 256) {
    int bb = i >> 9, k = i & 511;
    hc[bb][k] = (k < CH) ? h[bb * CH + k] : ctx[bb * CH + (k - CH)];
  }
  __syncthreads();
  int v = blockIdx.x * 256 + tid;
  float partial[CB];
#pragma unroll
  for (int bb = 0; bb < CB; ++bb) partial[bb] = 0.f;
  if (v < CV) {
    const float* wr = W_out + (size_t)v * (2 * CH);
    float acc[CB];
#pragma unroll
    for (int bb = 0; bb < CB; ++bb) acc[bb] = 0.f;
    for (int k = 0; k < 2 * CH; k += 4) {
      float4 w = *(const float4*)(wr + k);
#pragma unroll
      for (int bb = 0; bb < CB; ++bb) {
        float4 x = *(const float4*)(&hc[bb][k]);
        acc[bb] += x.x * w.x + x.y * w.y + x.z * w.z + x.w * w.w;
      }
    }
    float bo = b_out[v];
#pragma unroll
    for (int bb = 0; bb < CB; ++bb) {
      float e = expf(acc[bb] + bo);
      explog[(size_t)bb * CV + v] = e;
      partial[bb] = e;
    }
  }
  int lane = tid & 63;
#pragma unroll
  for (int bb = 0; bb < CB; ++bb) {
    float s = wave_sum(partial[bb]);
    if (lane == 0) atomicAdd(&rowsum[bb], s);
  }
}

// ---------------------------------------------------------------------------
// K3: final[b,v] = p_gen * explog/rowsum (v<V), 0 for OOV pad slots.
// ---------------------------------------------------------------------------
__global__ __launch_bounds__(256) void k3_final(
    int t, const float* __restrict__ explog, const float* __restrict__ rowsum,
    const float* __restrict__ p_gen, float* __restrict__ dout) {
  int vv = blockIdx.x * 256 + threadIdx.x;
  int b = blockIdx.y;
  if (vv >= CEXT) return;
  float val = 0.f;
  if (vv < CV) val = p_gen[b] * explog[(size_t)b * CV + vv] / rowsum[b];
  dout[((size_t)(b * CTM1 + t)) * CEXT + vv] = val;
}

// ---------------------------------------------------------------------------
// K4 epilogue: last step's scatter, hT/cT, coverage_loss. 1 block.
// ---------------------------------------------------------------------------
__global__ __launch_bounds__(1024) void k4_epilogue(
    const float* __restrict__ h, const float* __restrict__ c,
    const float* __restrict__ attn_ws, const float* __restrict__ p_gen_ws,
    const int* __restrict__ copy_idx, const float* __restrict__ covloss_ws,
    float* __restrict__ dout) {
  int tid = threadIdx.x;
  for (int i = tid; i < CB * CS; i += 1024) {
    int b = i / CS;
    float val = (1.f - p_gen_ws[b]) * attn_ws[i];
    atomicAdd(dout + ((size_t)(b * CTM1 + (CTM1 - 1))) * CEXT + copy_idx[i],
              val);
  }
  const size_t D0 = (size_t)CB * CTM1 * CEXT;
  for (int i = tid; i < CB * CH; i += 1024) {
    dout[D0 + i] = h[i];
    dout[D0 + CB * CH + i] = c[i];
  }
  float p = 0.f;
  for (int i = tid; i < CTM1 * CB; i += 1024) p += covloss_ws[i];
  __shared__ float red[16];
  float s = wave_sum(p);
  int lane = tid & 63, wid = tid >> 6;
  if (lane == 0) red[wid] = s;
  __syncthreads();
  if (tid == 0) {
    float t2 = 0.f;
    for (int i = 0; i < 16; ++i) t2 += red[i];
    dout[D0 + 2 * CB * CH] = t2 / (float)(CTM1 * CB);
  }
}

// ---------------------------------------------------------------------------
extern "C" void kernel_launch(void* const* d_in, const int* in_sizes, int n_in,
                              void* d_out, int out_size, void* d_ws,
                              size_t ws_size, hipStream_t stream) {
  const int* tgt = (const int*)d_in[0];
  const float* hidden = (const float*)d_in[1];
  const float* cell = (const float*)d_in[2];
  const float* enc = (const float*)d_in[3];
  const int* src_lens = (const int*)d_in[4];
  const int* src_ids = (const int*)d_in[5];
  const int* src_oov = (const int*)d_in[6];
  const float* embedding = (const float*)d_in[7];
  const float* W_h = (const float*)d_in[8];
  const float* W_s = (const float*)d_in[9];
  const float* w_c = (const float*)d_in[10];
  const float* v_vec = (const float*)d_in[11];
  const float* b_attn = (const float*)d_in[12];
  const float* W_ih = (const float*)d_in[13];
  const float* W_hh = (const float*)d_in[14];
  const float* b_ih = (const float*)d_in[15];
  const float* b_hh = (const float*)d_in[16];
  const float* W_pg = (const float*)d_in[17];
  const float* b_pg = (const float*)d_in[18];
  const float* W_out = (const float*)d_in[19];
  const float* b_out = (const float*)d_in[20];
  float* dout = (float*)d_out;

  // workspace layout
  char* base = (char*)d_ws;
  float* Wh_h = (float*)base;                       // B*S*H
  float* h = Wh_h + (size_t)CB * CS * CH;           // B*H
  float* c = h + CB * CH;                           // B*H
  float* cov = c + CB * CH;                         // B*S
  float* attn = cov + CB * CS;                      // B*S
  float* ctx = attn + CB * CS;                      // B*H
  float* p_gen = ctx + CB * CH;                     // B
  float* rowsum = p_gen + CB;                       // B
  float* covloss = rowsum + CB;                     // TM1*B
  float* explog = covloss + CTM1 * CB;              // B*V
  int* copy_idx = (int*)(explog + (size_t)CB * CV); // B*S ints
  unsigned short* A_bf16 = (unsigned short*)(copy_idx + CB * CS);  // 16*512
  unsigned short* Wb = A_bf16 + CB * 2 * CH;        // V*512 bf16

  size_t need = (size_t)((char*)(Wb + (size_t)CV * 2 * CH) - base);
  bool use_mfma = (ws_size >= need);

  if (use_mfma) {
    pw_convert<<<(CV * 2 * CH) / (256 * 8), 256, 0, stream>>>(W_out, Wb);
  }
  p0_precompute<<<CB * CS / 8, 256, 0, stream>>>(enc, W_h, hidden, cell,
                                                 src_ids, src_oov, Wh_h, h, c,
                                                 cov, copy_idx);
  for (int t = 0; t < CTM1; ++t) {
    k1_attn_lstm<<<CB, 1024, 0, stream>>>(
        t, tgt, enc, src_lens, embedding, W_s, w_c, v_vec, b_attn, W_ih, W_hh,
        b_ih, b_hh, W_pg, b_pg, Wh_h, copy_idx, h, c, cov, attn, ctx, p_gen,
        rowsum, covloss, use_mfma ? A_bf16 : (unsigned short*)nullptr, dout);
    if (use_mfma) {
      k2_logits_mfma<<<(CV + 63) / 64, 256, 0, stream>>>(Wb, b_out, A_bf16,
                                                         explog, rowsum);
    } else {
      k2_logits_fp32<<<(CV + 255) / 256, 256, 0, stream>>>(W_out, b_out, h,
                                                           ctx, explog,
                                                           rowsum);
    }
    k3_final<<<dim3((CEXT + 255) / 256, CB), 256, 0, stream>>>(t, explog,
                                                               rowsum, p_gen,
                                                               dout);
  }
  k4_epilogue<<<1, 1024, 0, stream>>>(h, c, attn, p_gen, copy_idx, covloss,
                                      dout);
}

// Round 3
// 3862.902 us; speedup vs baseline: 5.0434x; 2.6925x over previous
//
#include <hip/hip_runtime.h>
#include <math.h>

// Problem constants
#define CB 16
#define CS 400
#define CT 51
#define CTM1 50
#define CV 50000
#define CE 128
#define CH 256
#define CMAXOOV 50
#define CEXT (CV + CMAXOOV)
#define NCHUNK 8
#define SCHUNK 50          // CS / NCHUNK
#define CX 640             // E + H + H  (x = [emb|ctx|h])
#define CG 1024            // 4H
#define AXP 648            // padded LDS row (shorts) for A_x (81 short8)
#define VCHUNK 6256        // CEXT/8 rounded down

typedef __attribute__((ext_vector_type(4))) float f32x4;
typedef __attribute__((ext_vector_type(8))) short short8;

__device__ __forceinline__ float wave_sum(float x) {
#pragma unroll
  for (int o = 32; o > 0; o >>= 1) x += __shfl_xor(x, o);
  return x;
}
__device__ __forceinline__ float wave_max(float x) {
#pragma unroll
  for (int o = 32; o > 0; o >>= 1) x = fmaxf(x, __shfl_xor(x, o));
  return x;
}
__device__ __forceinline__ float sigm(float x) { return 1.f / (1.f + expf(-x)); }
__device__ __forceinline__ unsigned short f2bf(float f) {
  union { float f; unsigned u; } x;
  x.f = f;
  unsigned r = x.u + 0x7FFFu + ((x.u >> 16) & 1u);  // RNE
  return (unsigned short)(r >> 16);
}

// ---------------------------------------------------------------------------
// One-time weight prep
// ---------------------------------------------------------------------------
__global__ __launch_bounds__(256) void pw_convert(
    const float* __restrict__ W, unsigned short* __restrict__ Wb) {
  size_t i = ((size_t)blockIdx.x * 256 + threadIdx.x) * 8;
  float4 a = *(const float4*)(W + i);
  float4 b = *(const float4*)(W + i + 4);
  short8 o;
  o[0] = (short)f2bf(a.x); o[1] = (short)f2bf(a.y);
  o[2] = (short)f2bf(a.z); o[3] = (short)f2bf(a.w);
  o[4] = (short)f2bf(b.x); o[5] = (short)f2bf(b.y);
  o[6] = (short)f2bf(b.z); o[7] = (short)f2bf(b.w);
  *(short8*)(Wb + i) = o;
}

// Wcat[j][k] bf16: k<384 -> W_ih[j][k], else W_hh[j][k-384]. 1024x640.
__global__ __launch_bounds__(256) void pw_cat(
    const float* __restrict__ W_ih, const float* __restrict__ W_hh,
    unsigned short* __restrict__ Wcat) {
  int t8 = blockIdx.x * 256 + threadIdx.x;  // 81920 short8
  int j = t8 / 80, k8 = t8 % 80;
  short8 o;
#pragma unroll
  for (int i = 0; i < 8; ++i) {
    int k = k8 * 8 + i;
    float v = (k < CE + CH) ? W_ih[(size_t)j * (CE + CH) + k]
                            : W_hh[(size_t)j * CH + (k - (CE + CH))];
    o[i] = (short)f2bf(v);
  }
  *(short8*)(Wcat + (size_t)t8 * 8) = o;
}

// 256x256 fp32 transpose: out[j][k] = in[k][j]
__global__ __launch_bounds__(256) void pw_t256(const float* __restrict__ in,
                                               float* __restrict__ out) {
  int j = blockIdx.x, k = threadIdx.x;
  out[j * CH + k] = in[k * CH + j];
}

// ---------------------------------------------------------------------------
// P0: Wh_h = enc @ W_h^T via transposed W_h (coalesced); copy_idx; cov=0.
// 8 rows/block, grid = 800, 256 threads.
// ---------------------------------------------------------------------------
__global__ __launch_bounds__(256) void p0_precompute(
    const float* __restrict__ enc, const float* __restrict__ W_hT,
    const int* __restrict__ src_ids, const int* __restrict__ src_oov,
    float* __restrict__ Wh_h, float* __restrict__ cov,
    int* __restrict__ copy_idx) {
  const int row0 = blockIdx.x * 8, tid = threadIdx.x;
  __shared__ float erT[CH * 8];
#pragma unroll
  for (int i = 0; i < 8; ++i) {
    int idx = tid + i * 256;           // idx = r*256 + j
    int r = idx >> 8, j = idx & 255;
    erT[j * 8 + r] = enc[(size_t)row0 * CH + idx];
  }
  if (tid < 8) {
    int row = row0 + tid;
    int ov = src_oov[row];
    copy_idx[row] = (ov >= 0) ? (CV + ov) : src_ids[row];
    cov[row] = 0.f;
  }
  __syncthreads();
  float acc[8] = {0, 0, 0, 0, 0, 0, 0, 0};
#pragma unroll 4
  for (int j = 0; j < CH; ++j) {
    float w = W_hT[j * CH + tid];
    float4 e0 = *(const float4*)&erT[j * 8];
    float4 e1 = *(const float4*)&erT[j * 8 + 4];
    acc[0] += e0.x * w; acc[1] += e0.y * w; acc[2] += e0.z * w; acc[3] += e0.w * w;
    acc[4] += e1.x * w; acc[5] += e1.y * w; acc[6] += e1.z * w; acc[7] += e1.w * w;
  }
#pragma unroll
  for (int r = 0; r < 8; ++r) Wh_h[(size_t)(row0 + r) * CH + tid] = acc[r];
}

// ---------------------------------------------------------------------------
// P1: h/c init, hWs from h0 (coalesced via W_sT), A_x emb/h halves. grid=16.
// ---------------------------------------------------------------------------
__global__ __launch_bounds__(256) void p1_init(
    const int* __restrict__ tgt, const float* __restrict__ hidden,
    const float* __restrict__ cell, const float* __restrict__ embedding,
    const float* __restrict__ W_sT, float* __restrict__ h,
    float* __restrict__ c, float* __restrict__ hWs,
    unsigned short* __restrict__ Ax_g) {
  const int b = blockIdx.x, tid = threadIdx.x;
  __shared__ float h_sh[CH];
  float hv = hidden[b * CH + tid];
  h_sh[tid] = hv;
  h[b * CH + tid] = hv;
  c[b * CH + tid] = cell[b * CH + tid];
  Ax_g[b * CX + CE + CH + tid] = f2bf(hv);
  if (tid < CE)
    Ax_g[b * CX + tid] = f2bf(embedding[(size_t)tgt[b * CT] * CE + tid]);
  __syncthreads();
  float acc = 0.f;
#pragma unroll 8
  for (int j = 0; j < CH; ++j) acc += h_sh[j] * W_sT[j * CH + tid];
  hWs[b * CH + tid] = acc;
}

// ---------------------------------------------------------------------------
// K1a: attention scores for chunk + normalize previous dist row.
// grid = 128 (b*8+chunk), 256 threads.
// ---------------------------------------------------------------------------
__global__ __launch_bounds__(256) void k1a_scores(
    int t, const float* __restrict__ Wh_h, const float* __restrict__ hWs,
    const float* __restrict__ cov, const float* __restrict__ w_c,
    const float* __restrict__ v_vec, const float* __restrict__ b_attn,
    const int* __restrict__ src_lens, const float* __restrict__ explog,
    const float* __restrict__ p_gen, const float* __restrict__ rowsum,
    float* __restrict__ scores, float* __restrict__ dout) {
  const int b = blockIdx.x >> 3, chunk = blockIdx.x & 7;
  const int tid = threadIdx.x, lane = tid & 63, wid = tid >> 6;
  __shared__ float hws_sh[CH], wc_sh[CH], vv_sh[CH];
  hws_sh[tid] = hWs[b * CH + tid];
  wc_sh[tid] = w_c[tid];
  vv_sh[tid] = v_vec[tid];
  __syncthreads();
  if (t > 0) {  // normalize dout row (b, t-1): p_gen * explog / rowsum
    float inv = p_gen[b] / rowsum[b];
    float* drow = dout + ((size_t)(b * CTM1 + t - 1)) * CEXT;
    int vstart = chunk * VCHUNK;
    int vend = (chunk == 7) ? CEXT : vstart + VCHUNK;
    for (int v = vstart + tid; v < vend; v += 256)
      drow[v] = (v < CV) ? explog[(size_t)b * CV + v] * inv : 0.f;
  }
  const float ba = b_attn[0];
  const int len = src_lens[b];
  const int s0 = chunk * SCHUNK;
  const int k = lane * 4;
  for (int s = s0 + wid; s < s0 + SCHUNK; s += 4) {
    float cv = cov[b * CS + s];
    float4 w = *(const float4*)(Wh_h + ((size_t)(b * CS + s)) * CH + k);
    float p = tanhf(w.x + hws_sh[k] + cv * wc_sh[k] + ba) * vv_sh[k] +
              tanhf(w.y + hws_sh[k + 1] + cv * wc_sh[k + 1] + ba) * vv_sh[k + 1] +
              tanhf(w.z + hws_sh[k + 2] + cv * wc_sh[k + 2] + ba) * vv_sh[k + 2] +
              tanhf(w.w + hws_sh[k + 3] + cv * wc_sh[k + 3] + ba) * vv_sh[k + 3];
    p = wave_sum(p);
    if (lane == 0) scores[b * CS + s] = (s >= len) ? -1e9f : p;
  }
}

// ---------------------------------------------------------------------------
// K1c: prev copy-scatter + softmax (stats redundant per chunk) + cov/covloss
//      + partial context.  grid = 128 (b*8+chunk), 256 threads.
// ---------------------------------------------------------------------------
__global__ __launch_bounds__(256) void k1c_softmax_ctx(
    int t, const float* __restrict__ scores, const float* __restrict__ enc,
    const int* __restrict__ copy_idx, const float* __restrict__ p_gen,
    float* __restrict__ attn_ws, float* __restrict__ cov,
    float* __restrict__ covloss_p, float* __restrict__ pctx,
    float* __restrict__ dout) {
  const int b = blockIdx.x >> 3, chunk = blockIdx.x & 7;
  const int tid = threadIdx.x, lane = tid & 63, wid = tid >> 6;
  __shared__ float sm[CS];
  __shared__ float sh_a[SCHUNK];
  __shared__ float red[4];
  __shared__ float stat[2];
  sm[tid] = scores[b * CS + tid];
  if (tid < CS - 256) sm[tid + 256] = scores[b * CS + tid + 256];
  if (t > 0 && tid < SCHUNK) {  // scatter prev copy dist (row already normed)
    int s = chunk * SCHUNK + tid;
    float pg1 = 1.f - p_gen[b];
    atomicAdd(dout + ((size_t)(b * CTM1 + t - 1)) * CEXT + copy_idx[b * CS + s],
              pg1 * attn_ws[b * CS + s]);
  }
  __syncthreads();
  float lm = sm[tid];
  if (tid < CS - 256) lm = fmaxf(lm, sm[tid + 256]);
  lm = wave_max(lm);
  if (lane == 0) red[wid] = lm;
  __syncthreads();
  if (tid == 0) stat[0] = fmaxf(fmaxf(red[0], red[1]), fmaxf(red[2], red[3]));
  __syncthreads();
  float m = stat[0];
  float le = expf(sm[tid] - m);
  if (tid < CS - 256) le += expf(sm[tid + 256] - m);
  le = wave_sum(le);
  if (lane == 0) red[wid] = le;
  __syncthreads();
  if (tid == 0) stat[1] = red[0] + red[1] + red[2] + red[3];
  __syncthreads();
  float inv = 1.f / stat[1];
  float covp = 0.f;
  if (tid < SCHUNK) {
    int s = chunk * SCHUNK + tid;
    float a = expf(sm[s] - m) * inv;
    sh_a[tid] = a;
    attn_ws[b * CS + s] = a;
    float cv = cov[b * CS + s];
    covp = fminf(a, cv);
    cov[b * CS + s] = cv + a;
  }
  covp = wave_sum(covp);  // contributors all in wave 0
  if (tid == 0) covloss_p[(t * CB + b) * NCHUNK + chunk] = covp;
  __syncthreads();
  // partial context: thread owns k = tid
  float pc = 0.f;
  const float* er = enc + ((size_t)(b * CS + chunk * SCHUNK)) * CH + tid;
#pragma unroll 5
  for (int i = 0; i < SCHUNK; ++i) pc += sh_a[i] * er[(size_t)i * CH];
  pctx[(b * NCHUNK + chunk) * CH + tid] = pc;
}

// ---------------------------------------------------------------------------
// K1d: gates = x @ Wcat^T via MFMA bf16. x rows in LDS from Ax_g + pctx.
// grid = 16 blocks x 256 thr (4 waves); wave handles 16 j-columns.
// ---------------------------------------------------------------------------
__global__ __launch_bounds__(256) void k1d_gates(
    const unsigned short* __restrict__ Ax_g,
    const unsigned short* __restrict__ Wcat, const float* __restrict__ pctx,
    float* __restrict__ ctx_ws, float* __restrict__ gates) {
  const int tid = threadIdx.x, lane = tid & 63, wid = tid >> 6;
  __shared__ short axs[CB * AXP];
  short8* axs8 = (short8*)axs;
  const short8* ag8 = (const short8*)Ax_g;
#pragma unroll
  for (int i = 0; i < 5; ++i) {  // 1280 short8 = [16][80]
    int idx = tid + i * 256;
    int bb = idx / 80, c8 = idx % 80;
    axs8[bb * 81 + c8] = ag8[idx];
  }
  __syncthreads();
#pragma unroll
  for (int i = 0; i < 16; ++i) {  // ctx: 4096 (b,k)
    int idx = tid + i * 256;
    int bb = idx >> 8, k = idx & 255;
    float s = 0.f;
#pragma unroll
    for (int cc = 0; cc < NCHUNK; ++cc) s += pctx[(bb * NCHUNK + cc) * CH + k];
    if (blockIdx.x == 0) ctx_ws[bb * CH + k] = s;
    axs[bb * AXP + CE + k] = (short)f2bf(s);
  }
  __syncthreads();
  const int n0 = (blockIdx.x * 4 + wid) * 16;
  const int nn = lane & 15, g = lane >> 4;
  const short8* bp = (const short8*)Wcat + (size_t)(n0 + nn) * 80;
  f32x4 acc = {0.f, 0.f, 0.f, 0.f};
#pragma unroll
  for (int kt = 0; kt < 20; ++kt) {
    short8 af = axs8[nn * 81 + kt * 4 + g];
    short8 bf = bp[kt * 4 + g];
    acc = __builtin_amdgcn_mfma_f32_16x16x32_bf16(af, bf, acc, 0, 0, 0);
  }
#pragma unroll
  for (int r = 0; r < 4; ++r)
    gates[(size_t)(g * 4 + r) * CG + n0 + nn] = acc[r];
}

// ---------------------------------------------------------------------------
// K1e: cell/h update + p_gen + A writes + hWs(next) + rowsum=0. grid=16.
// ---------------------------------------------------------------------------
__global__ __launch_bounds__(256) void k1e_cell(
    int t, const int* __restrict__ tgt, const float* __restrict__ embedding,
    const float* __restrict__ gates, const float* __restrict__ ctx_ws,
    const float* __restrict__ b_ih, const float* __restrict__ b_hh,
    const float* __restrict__ W_pg, const float* __restrict__ b_pg,
    const float* __restrict__ W_sT, float* __restrict__ h,
    float* __restrict__ c, float* __restrict__ hWs, float* __restrict__ p_gen,
    float* __restrict__ rowsum, unsigned short* __restrict__ A_bf16,
    unsigned short* __restrict__ Ax_g) {
  const int b = blockIdx.x;
  const int tid = threadIdx.x, lane = tid & 63, wid = tid >> 6;
  __shared__ float hn_sh[CH], emb_sh[CE];
  __shared__ float red[4];
  float gi = gates[b * CG + tid] + b_ih[tid] + b_hh[tid];
  float gf = gates[b * CG + CH + tid] + b_ih[CH + tid] + b_hh[CH + tid];
  float gg = gates[b * CG + 2 * CH + tid] + b_ih[2 * CH + tid] + b_hh[2 * CH + tid];
  float go = gates[b * CG + 3 * CH + tid] + b_ih[3 * CH + tid] + b_hh[3 * CH + tid];
  float co = c[b * CH + tid];
  float cn = sigm(gf) * co + sigm(gi) * tanhf(gg);
  float hn = sigm(go) * tanhf(cn);
  c[b * CH + tid] = cn;
  h[b * CH + tid] = hn;
  hn_sh[tid] = hn;
  float cx = ctx_ws[b * CH + tid];
  if (tid < CE) emb_sh[tid] = embedding[(size_t)tgt[b * CT + t] * CE + tid];
  __syncthreads();
  // p_gen = sigmoid([h|ctx|emb] . W_pg + b_pg)
  float term = hn * W_pg[tid] + cx * W_pg[CH + tid];
  if (tid < CE) term += emb_sh[tid] * W_pg[2 * CH + tid];
  term = wave_sum(term);
  if (lane == 0) red[wid] = term;
  __syncthreads();
  if (tid == 0) {
    p_gen[b] = sigm(red[0] + red[1] + red[2] + red[3] + b_pg[0]);
    rowsum[b] = 0.f;
  }
  // A for k2: [h|ctx]
  A_bf16[b * 2 * CH + tid] = f2bf(hn);
  A_bf16[b * 2 * CH + CH + tid] = f2bf(cx);
  // A_x for next step: emb(t+1), h
  Ax_g[b * CX + CE + CH + tid] = f2bf(hn);
  if (tid < CE)
    Ax_g[b * CX + tid] =
        f2bf(embedding[(size_t)tgt[b * CT + t + 1] * CE + tid]);
  // hWs for next step (coalesced W_sT stream)
  float acc = 0.f;
#pragma unroll 8
  for (int j = 0; j < CH; ++j) acc += hn_sh[j] * W_sT[j * CH + tid];
  hWs[b * CH + tid] = acc;
}

// ---------------------------------------------------------------------------
// K2 (MFMA): explog[b,v] = exp([h|ctx].W_out[v,:] + b_out[v]); rowsum atomics.
// grid = ceil(V/64), 256 threads.
// ---------------------------------------------------------------------------
__global__ __launch_bounds__(256) void k2_logits_mfma(
    const unsigned short* __restrict__ Wb, const float* __restrict__ b_out,
    const unsigned short* __restrict__ A, float* __restrict__ explog,
    float* __restrict__ rowsum) {
  const int tid = threadIdx.x;
  const int lane = tid & 63, wid = tid >> 6;
  const int n = lane & 15, g = lane >> 4;
  const int v = blockIdx.x * 64 + wid * 16 + n;
  const bool ok = v < CV;
  const int vc = ok ? v : CV - 1;

  const short8* ap = (const short8*)A;
  const short8* bp = (const short8*)Wb;
  short8 af[16], bf[16];
#pragma unroll
  for (int kt = 0; kt < 16; ++kt) af[kt] = ap[n * 64 + kt * 4 + g];
#pragma unroll
  for (int kt = 0; kt < 16; ++kt) bf[kt] = bp[(size_t)vc * 64 + kt * 4 + g];

  f32x4 acc = {0.f, 0.f, 0.f, 0.f};
#pragma unroll
  for (int kt = 0; kt < 16; ++kt)
    acc = __builtin_amdgcn_mfma_f32_16x16x32_bf16(af[kt], bf[kt], acc, 0, 0, 0);

  float bo = ok ? b_out[v] : 0.f;
  float ev[4];
#pragma unroll
  for (int r = 0; r < 4; ++r) {
    float e = ok ? expf(acc[r] + bo) : 0.f;
    ev[r] = e;
    if (ok) explog[(size_t)(g * 4 + r) * CV + v] = e;
  }
#pragma unroll
  for (int r = 0; r < 4; ++r) {
#pragma unroll
    for (int o = 1; o < 16; o <<= 1) ev[r] += __shfl_xor(ev[r], o);
  }
  __shared__ float prs[4][16];
  if ((lane & 15) == 0) {
#pragma unroll
    for (int r = 0; r < 4; ++r) prs[wid][g * 4 + r] = ev[r];
  }
  __syncthreads();
  if (tid < 16) {
    float s = prs[0][tid] + prs[1][tid] + prs[2][tid] + prs[3][tid];
    atomicAdd(&rowsum[tid], s);
  }
}

// ---------------------------------------------------------------------------
// K4a: normalize final dist row (t = 49). grid = 128.
// ---------------------------------------------------------------------------
__global__ __launch_bounds__(256) void k4a_norm(
    const float* __restrict__ explog, const float* __restrict__ p_gen,
    const float* __restrict__ rowsum, float* __restrict__ dout) {
  const int b = blockIdx.x >> 3, chunk = blockIdx.x & 7;
  const int tid = threadIdx.x;
  float inv = p_gen[b] / rowsum[b];
  float* drow = dout + ((size_t)(b * CTM1 + CTM1 - 1)) * CEXT;
  int vstart = chunk * VCHUNK;
  int vend = (chunk == 7) ? CEXT : vstart + VCHUNK;
  for (int v = vstart + tid; v < vend; v += 256)
    drow[v] = (v < CV) ? explog[(size_t)b * CV + v] * inv : 0.f;
}

// ---------------------------------------------------------------------------
// K4b: final scatter + hT/cT + coverage_loss. grid = 16.
// ---------------------------------------------------------------------------
__global__ __launch_bounds__(256) void k4b_tail(
    const float* __restrict__ h, const float* __restrict__ c,
    const float* __restrict__ attn_ws, const float* __restrict__ p_gen,
    const int* __restrict__ copy_idx, const float* __restrict__ covloss_p,
    float* __restrict__ dout) {
  const int b = blockIdx.x, tid = threadIdx.x, lane = tid & 63, wid = tid >> 6;
  __shared__ float red[4];
  float pg1 = 1.f - p_gen[b];
  for (int s = tid; s < CS; s += 256)
    atomicAdd(dout + ((size_t)(b * CTM1 + CTM1 - 1)) * CEXT + copy_idx[b * CS + s],
              pg1 * attn_ws[b * CS + s]);
  const size_t D0 = (size_t)CB * CTM1 * CEXT;
  dout[D0 + b * CH + tid] = h[b * CH + tid];
  dout[D0 + CB * CH + b * CH + tid] = c[b * CH + tid];
  if (b == 0) {
    float p = 0.f;
    for (int i = tid; i < CTM1 * CB * NCHUNK; i += 256) p += covloss_p[i];
    p = wave_sum(p);
    if (lane == 0) red[wid] = p;
    __syncthreads();
    if (tid == 0)
      dout[D0 + 2 * CB * CH] =
          (red[0] + red[1] + red[2] + red[3]) / (float)(CTM1 * CB);
  }
}

// ---------------------------------------------------------------------------
extern "C" void kernel_launch(void* const* d_in, const int* in_sizes, int n_in,
                              void* d_out, int out_size, void* d_ws,
                              size_t ws_size, hipStream_t stream) {
  const int* tgt = (const int*)d_in[0];
  const float* hidden = (const float*)d_in[1];
  const float* cell = (const float*)d_in[2];
  const float* enc = (const float*)d_in[3];
  const int* src_lens = (const int*)d_in[4];
  const int* src_ids = (const int*)d_in[5];
  const int* src_oov = (const int*)d_in[6];
  const float* embedding = (const float*)d_in[7];
  const float* W_h = (const float*)d_in[8];
  const float* W_s = (const float*)d_in[9];
  const float* w_c = (const float*)d_in[10];
  const float* v_vec = (const float*)d_in[11];
  const float* b_attn = (const float*)d_in[12];
  const float* W_ih = (const float*)d_in[13];
  const float* W_hh = (const float*)d_in[14];
  const float* b_ih = (const float*)d_in[15];
  const float* b_hh = (const float*)d_in[16];
  const float* W_pg = (const float*)d_in[17];
  const float* b_pg = (const float*)d_in[18];
  const float* W_out = (const float*)d_in[19];
  const float* b_out = (const float*)d_in[20];
  float* dout = (float*)d_out;

  // workspace layout (16B alignment maintained for the bf16 blocks)
  float* ws = (float*)d_ws;
  float* Wh_h = ws;                                 // 1,638,400
  float* scores = Wh_h + (size_t)CB * CS * CH;      // 6,400
  float* h = scores + CB * CS;                      // 4,096
  float* c = h + CB * CH;                           // 4,096
  float* cov = c + CB * CH;                         // 6,400
  float* attn = cov + CB * CS;                      // 6,400
  float* ctx = attn + CB * CS;                      // 4,096
  float* hWs = ctx + CB * CH;                       // 4,096
  float* p_gen = hWs + CB * CH;                     // 16
  float* rowsum = p_gen + CB;                       // 16
  float* covloss_p = rowsum + CB;                   // 6,400
  float* pctx = covloss_p + CTM1 * CB * NCHUNK;     // 32,768
  float* gates = pctx + CB * NCHUNK * CH;           // 16,384
  float* explog = gates + CB * CG;                  // 800,000
  float* W_sT = explog + (size_t)CB * CV;           // 65,536
  float* W_hT = W_sT + CH * CH;                     // 65,536
  int* copy_idx = (int*)(W_hT + CH * CH);           // 6,400 ints
  unsigned short* A_bf16 = (unsigned short*)(copy_idx + CB * CS);  // 8,192
  unsigned short* Ax_g = A_bf16 + CB * 2 * CH;      // 10,240
  unsigned short* Wcat = Ax_g + CB * CX;            // 655,360
  unsigned short* Wb = Wcat + (size_t)CG * CX;      // 25,600,000

  // one-time weight prep
  pw_convert<<<(CV * 2 * CH) / (256 * 8), 256, 0, stream>>>(W_out, Wb);
  pw_cat<<<(CG * CX / 8) / 256, 256, 0, stream>>>(W_ih, W_hh, Wcat);
  pw_t256<<<CH, CH, 0, stream>>>(W_s, W_sT);
  pw_t256<<<CH, CH, 0, stream>>>(W_h, W_hT);

  p0_precompute<<<CB * CS / 8, 256, 0, stream>>>(enc, W_hT, src_ids, src_oov,
                                                 Wh_h, cov, copy_idx);
  p1_init<<<CB, 256, 0, stream>>>(tgt, hidden, cell, embedding, W_sT, h, c,
                                  hWs, Ax_g);

  for (int t = 0; t < CTM1; ++t) {
    k1a_scores<<<CB * NCHUNK, 256, 0, stream>>>(
        t, Wh_h, hWs, cov, w_c, v_vec, b_attn, src_lens, explog, p_gen, rowsum,
        scores, dout);
    k1c_softmax_ctx<<<CB * NCHUNK, 256, 0, stream>>>(
        t, scores, enc, copy_idx, p_gen, attn, cov, covloss_p, pctx, dout);
    k1d_gates<<<CB, 256, 0, stream>>>(Ax_g, Wcat, pctx, ctx, gates);
    k1e_cell<<<CB, 256, 0, stream>>>(t, tgt, embedding, gates, ctx, b_ih, b_hh,
                                     W_pg, b_pg, W_sT, h, c, hWs, p_gen,
                                     rowsum, A_bf16, Ax_g);
    k2_logits_mfma<<<(CV + 63) / 64, 256, 0, stream>>>(Wb, b_out, A_bf16,
                                                       explog, rowsum);
  }
  k4a_norm<<<CB * NCHUNK, 256, 0, stream>>>(explog, p_gen, rowsum, dout);
  k4b_tail<<<CB, 256, 0, stream>>>(h, c, attn, p_gen, copy_idx, covloss_p,
                                   dout);
}